// Round 6
// baseline (121.208 us; speedup 1.0000x reference)
//
#include <hip/hip_runtime.h>
#include <cmath>

typedef float f32x4 __attribute__((ext_vector_type(4)));
typedef float f32x2 __attribute__((ext_vector_type(2)));

#define TT 8192
#define NV 65
#define NBLK 640

__device__ __forceinline__ float dot4acc(f32x4 a, f32x4 b, float acc) {
  acc = fmaf(a[0], b[0], acc);
  acc = fmaf(a[1], b[1], acc);
  acc = fmaf(a[2], b[2], acc);
  acc = fmaf(a[3], b[3], acc);
  return acc;
}

// Kernel A: cpt[b*6+e][t] = softmax(embed_w[x])[b,t,e]; also zeroes wsum.
__global__ __launch_bounds__(128) void cp_kernel(const int* __restrict__ x,
                                                 const float* __restrict__ ew,
                                                 float* __restrict__ cpt,
                                                 float* __restrict__ wsum) {
  int n = blockIdx.x * 128 + threadIdx.x;  // n = b*8192 + t, 256 blocks
  int b = n >> 13, t = n & 8191;
  int xv = x[n];
  float v[6];
#pragma unroll
  for (int e = 0; e < 6; ++e) v[e] = ew[xv * 6 + e];
  float m = v[0];
#pragma unroll
  for (int e = 1; e < 6; ++e) m = fmaxf(m, v[e]);
  float s = 0.f;
#pragma unroll
  for (int e = 0; e < 6; ++e) { v[e] = expf(v[e] - m); s += v[e]; }
  float inv = 1.f / s;
#pragma unroll
  for (int e = 0; e < 6; ++e) cpt[(b * 6 + e) * TT + t] = v[e] * inv;
  f32x2 z2 = {0.f, 0.f};
#pragma unroll
  for (int i = 0; i < 3; ++i)
    *reinterpret_cast<f32x2*>(&wsum[6 * n + 2 * i]) = z2;
}

// Kernel B: wsum[t][24] += tril(W)[32-row x 2048-k tile] @ cp.
// No LDS, no __syncthreads, free-running waves. Lane = (esel=lane>>5,
// k32=lane&31). Each lane: 8 rows x 12 e -> acc[8][12] = 96 VGPR.
// cp straight from L2 (12 B/row-k = 0.4 GB total, under W-stream time);
// W nontemporal, prefetched one iter ahead; esel-halves' duplicate W
// addresses dedup in the coalescer. Per-wave early exit past diagonal.
// __launch_bounds__(256,1): never trade acc registers for occupancy.
__global__ __launch_bounds__(256, 1) void sticky_B(const float* __restrict__ W,
                                                   const float* __restrict__ cpt,
                                                   float* __restrict__ wsum) {
  // bid -> (rt, kt): 388 full 2048-k tiles first, then 252 partials
  // (longest-first). Row-tile rt covers rows [32rt, 32rt+32).
  int bid = blockIdx.x;
  int rt, kt;
  if (bid < 193) { rt = 63 + bid; kt = 0; }
  else if (bid < 322) { rt = 127 + (bid - 193); kt = 1; }
  else if (bid < 387) { rt = 191 + (bid - 322); kt = 2; }
  else if (bid == 387) { rt = 255; kt = 3; }
  else {
    int q = 639 - bid;  // 251..0, longest partials first
    rt = q + (q >= 63) + (q >= 126) + (q >= 189);
    kt = (rt + 1) >> 6;
  }

  const int tid = threadIdx.x;
  const int w = tid >> 6;
  const int lane = tid & 63;
  const int esel = lane >> 5, k32 = lane & 31;
  const int R = rt * 32;
  const int r0 = R + 8 * w;          // this wave's 8 rows
  const int eb = 12 * esel;          // this lane's e-half
  const int k0 = kt * 2048;
  const int kend = min(k0 + 2048, R + 32);
  const int nit = (kend - k0 + 127) >> 7;                 // 128 k per iter
  const int nit_w = min(nit, (r0 + 8 - k0 + 127) >> 7);   // early diag exit

  float acc[8][12];
#pragma unroll
  for (int r = 0; r < 8; ++r)
#pragma unroll
    for (int e2 = 0; e2 < 12; ++e2) acc[r][e2] = 0.f;

  // tril zeros mean in-tile over-read past the diagonal adds exactly 0;
  // all addresses stay inside the 8192x8192 allocation.
  f32x4 wv[8], wn[8];
  {
    const int koff = k0 + k32 * 4;
#pragma unroll
    for (int r = 0; r < 8; ++r)
      wv[r] = __builtin_nontemporal_load(
          reinterpret_cast<const f32x4*>(&W[(r0 + r) * TT + koff]));
  }
#pragma unroll 1
  for (int it = 0; it < nit_w; ++it) {
    const int koff = k0 + it * 128 + k32 * 4;
    const int knxt = (it + 1 < nit_w) ? koff + 128 : koff;
#pragma unroll
    for (int r = 0; r < 8; ++r)
      wn[r] = __builtin_nontemporal_load(
          reinterpret_cast<const f32x4*>(&W[(r0 + r) * TT + knxt]));
#pragma unroll
    for (int e2 = 0; e2 < 12; ++e2) {
      f32x4 c = *reinterpret_cast<const f32x4*>(&cpt[(eb + e2) * TT + koff]);
#pragma unroll
      for (int r = 0; r < 8; ++r) acc[r][e2] = dot4acc(wv[r], c, acc[r][e2]);
    }
#pragma unroll
    for (int r = 0; r < 8; ++r) wv[r] = wn[r];
  }

  // reduce the 32-way k split within each esel half (xor<32 stays in half)
#pragma unroll
  for (int r = 0; r < 8; ++r)
#pragma unroll
    for (int e2 = 0; e2 < 12; ++e2) {
      float v = acc[r][e2];
      v += __shfl_xor(v, 1);
      v += __shfl_xor(v, 2);
      v += __shfl_xor(v, 4);
      v += __shfl_xor(v, 8);
      v += __shfl_xor(v, 16);
      if (k32 == ((r * 12 + e2) & 31))
        atomicAdd(&wsum[(r0 + r) * 24 + eb + e2], v);
    }
}

// Kernel C: one thread per output element, out[b][t][v].
__global__ __launch_bounds__(256) void epi_kernel(
    const float* __restrict__ cpt, const float* __restrict__ wsum,
    const float* __restrict__ rtp, const float* __restrict__ tp,
    const float* __restrict__ CT, const float* __restrict__ RT,
    const float* __restrict__ OM, float* __restrict__ out) {
  int n = blockIdx.x * 256 + threadIdx.x;  // exactly 4*8192*65 threads
  int bt = n / NV;
  int v = n - bt * NV;
  int b = bt >> 13, t = bt & 8191;
  float cp6[6], ws6[6];
#pragma unroll
  for (int e = 0; e < 6; ++e) {
    cp6[e] = cpt[(b * 6 + e) * TT + t];
    ws6[e] = wsum[t * 24 + b * 6 + e];
  }
  float score = 0.f;
#pragma unroll
  for (int e = 0; e < 6; ++e) score = fmaf(cp6[e], ws6[e], score);
  float rt = rtp[0];
  float temp = tp[0];
  float z = (score - rt * rt) / (temp * temp);
  float reset = 1.f / (1.f + expf(-z));  // saturates correctly at extremes
  float o = 0.f;
#pragma unroll
  for (int c = 0; c < 6; ++c) {
    float tc = 0.f, rc = 0.f;
#pragma unroll
    for (int e = 0; e < 6; ++e) {
      tc = fmaf(cp6[e], CT[e * 6 + c], tc);
      rc = fmaf(cp6[e], RT[e * 6 + c], rc);
    }
    float nc = reset * rc + (1.f - reset) * tc;
    o = fmaf(nc, OM[c * NV + v], o);
  }
  out[n] = o;
}

extern "C" void kernel_launch(void* const* d_in, const int* in_sizes, int n_in,
                              void* d_out, int out_size, void* d_ws, size_t ws_size,
                              hipStream_t stream) {
  const int* x = (const int*)d_in[0];
  const float* ew = (const float*)d_in[1];
  const float* W = (const float*)d_in[2];
  const float* rtp = (const float*)d_in[3];
  const float* tp = (const float*)d_in[4];
  const float* CT = (const float*)d_in[5];
  const float* RT = (const float*)d_in[6];
  const float* OM = (const float*)d_in[7];
  float* out = (float*)d_out;
  float* cpt = (float*)d_ws;             // 24*8192 f32 = 786 KB
  float* wsum = (float*)d_ws + 24 * TT;  // 8192*24 f32 = 786 KB

  hipLaunchKernelGGL(cp_kernel, dim3(256), dim3(128), 0, stream, x, ew, cpt, wsum);
  hipLaunchKernelGGL(sticky_B, dim3(NBLK), dim3(256), 0, stream, W, cpt, wsum);
  int nout = 4 * TT * NV;  // 2,129,920 = 8320 * 256 exactly
  hipLaunchKernelGGL(epi_kernel, dim3(nout / 256), dim3(256), 0, stream,
                     cpt, wsum, rtp, tp, CT, RT, OM, out);
}

// Round 7
// 100.115 us; speedup vs baseline: 1.2107x; 1.2107x over previous
//
#include <hip/hip_runtime.h>
#include <cmath>

typedef float f32x4 __attribute__((ext_vector_type(4)));
typedef float f32x2 __attribute__((ext_vector_type(2)));

#define TT 8192
#define NV 65
#define NBLK 1280

__device__ __forceinline__ float dot4acc(f32x4 a, f32x4 b, float acc) {
  acc = fmaf(a[0], b[0], acc);
  acc = fmaf(a[1], b[1], acc);
  acc = fmaf(a[2], b[2], acc);
  acc = fmaf(a[3], b[3], acc);
  return acc;
}

// Kernel A: cpt[b*6+e][t] = softmax(embed_w[x])[b,t,e]; also zeroes wsum.
__global__ __launch_bounds__(128) void cp_kernel(const int* __restrict__ x,
                                                 const float* __restrict__ ew,
                                                 float* __restrict__ cpt,
                                                 float* __restrict__ wsum) {
  int n = blockIdx.x * 128 + threadIdx.x;  // n = b*8192 + t, 256 blocks
  int b = n >> 13, t = n & 8191;
  int xv = x[n];
  float v[6];
#pragma unroll
  for (int e = 0; e < 6; ++e) v[e] = ew[xv * 6 + e];
  float m = v[0];
#pragma unroll
  for (int e = 1; e < 6; ++e) m = fmaxf(m, v[e]);
  float s = 0.f;
#pragma unroll
  for (int e = 0; e < 6; ++e) { v[e] = expf(v[e] - m); s += v[e]; }
  float inv = 1.f / s;
#pragma unroll
  for (int e = 0; e < 6; ++e) cpt[(b * 6 + e) * TT + t] = v[e] * inv;
  f32x2 z2 = {0.f, 0.f};
#pragma unroll
  for (int i = 0; i < 3; ++i)
    *reinterpret_cast<f32x2*>(&wsum[6 * n + 2 * i]) = z2;
}

// Kernel B: wsum[t][24] += tril(W)[16-row x 2048-k tile] @ cp.
// OCCUPANCY-FIRST: lane state ~100 VGPR, __launch_bounds__(256,4) -> 4
// waves/SIMD guaranteed, no spill (acc[4][6]=24 regs only). Free-running
// waves (no LDS, no syncthreads); c from L2 (16 fmaf reuse per load);
// W nontemporal + 1-iter prefetch. 1280 near-uniform blocks, full tiles
// dispatched first; per-wave early exit past its diagonal.
__global__ __launch_bounds__(256, 4) void sticky_B(const float* __restrict__ W,
                                                   const float* __restrict__ cpt,
                                                   float* __restrict__ wsum) {
  // bid -> (rt, kt); 772 full 2048-k tiles first, then 508 partials
  int bid = blockIdx.x;
  int rt, kt;
  if (bid < 385) { rt = 127 + bid; kt = 0; }
  else if (bid < 642) { rt = 255 + (bid - 385); kt = 1; }
  else if (bid < 771) { rt = 383 + (bid - 642); kt = 2; }
  else if (bid == 771) { rt = 511; kt = 3; }
  else {
    int q = bid - 772;            // 0..507
    int m = q / 127, rl = q - 127 * m;
    rt = 128 * m + (126 - rl);    // longest partial in band first
    kt = m;
  }

  const int tid = threadIdx.x;
  const int w = tid >> 6, lane = tid & 63;
  const int esel = lane >> 4, k16 = lane & 15;  // esel = batch b
  const int R = rt * 16;
  const int r0 = R + 4 * w;      // this wave's 4 rows
  const int eb = 6 * esel;       // this lane's be-group (one batch)
  const int k0 = kt * 2048;
  const int kend = min(k0 + 2048, R + 16);
  const int klim = min(kend, r0 + 4);              // wave diagonal limit
  const int nit = max(0, (klim - k0 + 63) >> 6);   // 64 k per iter

  float acc[4][6];
#pragma unroll
  for (int r = 0; r < 4; ++r)
#pragma unroll
    for (int e = 0; e < 6; ++e) acc[r][e] = 0.f;

  if (nit > 0) {
    const float* wbase = W + (size_t)r0 * TT;
    f32x4 wv[4], wn[4];
    // tril zeros: in-tile over-read past the diagonal adds exactly 0; all
    // addresses stay inside the row (kend rounded to 64 stays <= 8192).
    {
      const int koff = k0 + k16 * 4;
#pragma unroll
      for (int r = 0; r < 4; ++r)
        wv[r] = __builtin_nontemporal_load(
            reinterpret_cast<const f32x4*>(wbase + r * TT + koff));
    }
#pragma unroll 1
    for (int it = 0; it < nit; ++it) {
      const int koff = k0 + it * 64 + k16 * 4;
      const int knxt = (it + 1 < nit) ? koff + 64 : koff;
#pragma unroll
      for (int r = 0; r < 4; ++r)
        wn[r] = __builtin_nontemporal_load(
            reinterpret_cast<const f32x4*>(wbase + r * TT + knxt));
#pragma unroll
      for (int e = 0; e < 6; ++e) {
        f32x4 c = *reinterpret_cast<const f32x4*>(&cpt[(eb + e) * TT + koff]);
#pragma unroll
        for (int r = 0; r < 4; ++r) acc[r][e] = dot4acc(wv[r], c, acc[r][e]);
      }
#pragma unroll
      for (int r = 0; r < 4; ++r) wv[r] = wn[r];
    }
  }

  // butterfly over the 16-way k split (stays within each 16-lane group)
#pragma unroll
  for (int r = 0; r < 4; ++r)
#pragma unroll
    for (int e = 0; e < 6; ++e) {
      float v = acc[r][e];
      v += __shfl_xor(v, 1);
      v += __shfl_xor(v, 2);
      v += __shfl_xor(v, 4);
      v += __shfl_xor(v, 8);
      int idx = r * 6 + e;
      if (k16 == (idx & 15))
        atomicAdd(&wsum[(r0 + r) * 24 + eb + e], v);
    }
}

// Kernel C: one thread per output element, out[b][t][v].
__global__ __launch_bounds__(256) void epi_kernel(
    const float* __restrict__ cpt, const float* __restrict__ wsum,
    const float* __restrict__ rtp, const float* __restrict__ tp,
    const float* __restrict__ CT, const float* __restrict__ RT,
    const float* __restrict__ OM, float* __restrict__ out) {
  int n = blockIdx.x * 256 + threadIdx.x;  // exactly 4*8192*65 threads
  int bt = n / NV;
  int v = n - bt * NV;
  int b = bt >> 13, t = bt & 8191;
  float cp6[6], ws6[6];
#pragma unroll
  for (int e = 0; e < 6; ++e) {
    cp6[e] = cpt[(b * 6 + e) * TT + t];
    ws6[e] = wsum[t * 24 + b * 6 + e];
  }
  float score = 0.f;
#pragma unroll
  for (int e = 0; e < 6; ++e) score = fmaf(cp6[e], ws6[e], score);
  float rt = rtp[0];
  float temp = tp[0];
  float z = (score - rt * rt) / (temp * temp);
  float reset = 1.f / (1.f + expf(-z));  // saturates correctly at extremes
  float o = 0.f;
#pragma unroll
  for (int c = 0; c < 6; ++c) {
    float tc = 0.f, rc = 0.f;
#pragma unroll
    for (int e = 0; e < 6; ++e) {
      tc = fmaf(cp6[e], CT[e * 6 + c], tc);
      rc = fmaf(cp6[e], RT[e * 6 + c], rc);
    }
    float nc = reset * rc + (1.f - reset) * tc;
    o = fmaf(nc, OM[c * NV + v], o);
  }
  out[n] = o;
}

extern "C" void kernel_launch(void* const* d_in, const int* in_sizes, int n_in,
                              void* d_out, int out_size, void* d_ws, size_t ws_size,
                              hipStream_t stream) {
  const int* x = (const int*)d_in[0];
  const float* ew = (const float*)d_in[1];
  const float* W = (const float*)d_in[2];
  const float* rtp = (const float*)d_in[3];
  const float* tp = (const float*)d_in[4];
  const float* CT = (const float*)d_in[5];
  const float* RT = (const float*)d_in[6];
  const float* OM = (const float*)d_in[7];
  float* out = (float*)d_out;
  float* cpt = (float*)d_ws;             // 24*8192 f32 = 786 KB
  float* wsum = (float*)d_ws + 24 * TT;  // 8192*24 f32 = 786 KB

  hipLaunchKernelGGL(cp_kernel, dim3(256), dim3(128), 0, stream, x, ew, cpt, wsum);
  hipLaunchKernelGGL(sticky_B, dim3(NBLK), dim3(256), 0, stream, W, cpt, wsum);
  int nout = 4 * TT * NV;  // 2,129,920 = 8320 * 256 exactly
  hipLaunchKernelGGL(epi_kernel, dim3(nout / 256), dim3(256), 0, stream,
                     cpt, wsum, rtp, tp, CT, RT, OM, out);
}

// Round 8
// 75.998 us; speedup vs baseline: 1.5949x; 1.3173x over previous
//
#include <hip/hip_runtime.h>
#include <cmath>

typedef float f32x4 __attribute__((ext_vector_type(4)));

#define TT 8192
#define NV 65

__device__ __forceinline__ float dot4acc(f32x4 a, f32x4 b, float acc) {
  acc = fmaf(a[0], b[0], acc);
  acc = fmaf(a[1], b[1], acc);
  acc = fmaf(a[2], b[2], acc);
  acc = fmaf(a[3], b[3], acc);
  return acc;
}

// Kernel A: cpt[b*6+e][t] = softmax(embed_w[x])[b,t,e]
__global__ __launch_bounds__(128) void cp_kernel(const int* __restrict__ x,
                                                 const float* __restrict__ ew,
                                                 float* __restrict__ cpt) {
  int n = blockIdx.x * 128 + threadIdx.x;  // n = b*8192 + t, 256 blocks
  int b = n >> 13, t = n & 8191;
  int xv = x[n];
  float v[6];
#pragma unroll
  for (int e = 0; e < 6; ++e) v[e] = ew[xv * 6 + e];
  float m = v[0];
#pragma unroll
  for (int e = 1; e < 6; ++e) m = fmaxf(m, v[e]);
  float s = 0.f;
#pragma unroll
  for (int e = 0; e < 6; ++e) { v[e] = expf(v[e] - m); s += v[e]; }
  float inv = 1.f / s;
#pragma unroll
  for (int e = 0; e < 6; ++e) cpt[(b * 6 + e) * TT + t] = v[e] * inv;
}

// Fused main kernel — R1 structure with wave-level row pairing.
// Block j: rows [8j,8j+8) (low) + [8184-8j, 8192-8j) (high); wave w owns
// low {8j+2w, 8j+2w+1} and high {8184-8j+2w, +1}. High rows keep every
// wave busy for the whole k-sweep; low rows are a predicated extra branch
// that shuts off past their diagonal (R1's idle-wave waste eliminated).
// Rows complete in-block -> butterfly + fused epilogue, no atomics/wsum.
__global__ __launch_bounds__(256, 2) void sticky_fused(
    const float* __restrict__ W, const float* __restrict__ cpt,
    const float* __restrict__ rtp, const float* __restrict__ tp,
    const float* __restrict__ CT, const float* __restrict__ RT,
    const float* __restrict__ OM, float* __restrict__ out) {
  __shared__ __align__(16) float cp_lds[24][256];
  __shared__ float ws_lds[4][4][24];
  const int j = blockIdx.x;            // j ascending = longest blocks first
  const int tid = threadIdx.x;
  const int w = tid >> 6, lane = tid & 63;
  const int kl = lane * 4;
  const int l0 = 8 * j + 2 * w;        // low rows: l0, l0+1
  const int h0 = 8184 - 8 * j + 2 * w; // high rows: h0, h0+1
  const int klow_end = l0 + 2;         // low rows active while kc < klow_end
  const int k_need = 8192 - 8 * j;     // block-uniform sweep extent
  const int nch = (k_need + 255) >> 8; // nch*256 <= 8192 always

  const float* wl = W + (size_t)l0 * TT;
  const float* wh = W + (size_t)h0 * TT;

  float acc[4][24];                    // rows {l0, l0+1, h0, h0+1} x 24 be
#pragma unroll
  for (int r = 0; r < 4; ++r)
#pragma unroll
    for (int e = 0; e < 24; ++e) acc[r][e] = 0.f;

#pragma unroll 1
  for (int ch = 0; ch < nch; ++ch) {
    const int kc = ch << 8;
    __syncthreads();
    // stage cp[24][kc..kc+256) into LDS (24 KB); kc+256 <= 8192 so all
    // addresses are in-bounds, no clamping needed
#pragma unroll
    for (int i = 0; i < 6; ++i) {
      int f = tid + 256 * i;
      int e = f >> 6, c4 = (f & 63) * 4;
      *reinterpret_cast<f32x4*>(&cp_lds[e][c4]) =
          *reinterpret_cast<const f32x4*>(&cpt[e * TT + kc + c4]);
    }
    __syncthreads();
    // high rows: active every chunk (their diagonal ~= k_need). Upper-tri
    // entries of position_mask are exactly 0 (tril in setup), so the <=7
    // element over-read past a high row's diagonal adds exactly 0.
    f32x4 wh0 = __builtin_nontemporal_load(
        reinterpret_cast<const f32x4*>(wh + kc + kl));
    f32x4 wh1 = __builtin_nontemporal_load(
        reinterpret_cast<const f32x4*>(wh + TT + kc + kl));
    if (kc < klow_end) {  // wave-uniform: low rows still before diagonal
      f32x4 wl0 = __builtin_nontemporal_load(
          reinterpret_cast<const f32x4*>(wl + kc + kl));
      f32x4 wl1 = __builtin_nontemporal_load(
          reinterpret_cast<const f32x4*>(wl + TT + kc + kl));
#pragma unroll
      for (int e = 0; e < 24; ++e) {
        f32x4 c = *reinterpret_cast<const f32x4*>(&cp_lds[e][kl]);
        acc[0][e] = dot4acc(wl0, c, acc[0][e]);
        acc[1][e] = dot4acc(wl1, c, acc[1][e]);
        acc[2][e] = dot4acc(wh0, c, acc[2][e]);
        acc[3][e] = dot4acc(wh1, c, acc[3][e]);
      }
    } else {
#pragma unroll
      for (int e = 0; e < 24; ++e) {
        f32x4 c = *reinterpret_cast<const f32x4*>(&cp_lds[e][kl]);
        acc[2][e] = dot4acc(wh0, c, acc[2][e]);
        acc[3][e] = dot4acc(wh1, c, acc[3][e]);
      }
    }
  }

  // full 64-lane butterfly over the k split
#pragma unroll
  for (int r = 0; r < 4; ++r)
#pragma unroll
    for (int e = 0; e < 24; ++e) {
      float v = acc[r][e];
      v += __shfl_xor(v, 1);
      v += __shfl_xor(v, 2);
      v += __shfl_xor(v, 4);
      v += __shfl_xor(v, 8);
      v += __shfl_xor(v, 16);
      v += __shfl_xor(v, 32);
      acc[r][e] = v;
    }
  if (lane == 0) {
#pragma unroll
    for (int r = 0; r < 4; ++r)
#pragma unroll
      for (int e = 0; e < 24; ++e) ws_lds[w][r][e] = acc[r][e];
  }
  __syncthreads();

  // fused epilogue (R1-proven): lane -> (r,b) + v-chunk over this wave's rows
  const int rb = lane & 15;
  const int r = rb >> 2, b = rb & 3, vi = lane >> 4;
  const int t = (r < 2) ? (l0 + r) : (h0 + (r - 2));
  float cp6[6], ws6[6];
#pragma unroll
  for (int e = 0; e < 6; ++e) {
    cp6[e] = cpt[(b * 6 + e) * TT + t];
    ws6[e] = ws_lds[w][r][b * 6 + e];
  }
  float score = 0.f;
#pragma unroll
  for (int e = 0; e < 6; ++e) score = fmaf(cp6[e], ws6[e], score);
  float rt = rtp[0];
  float temp = tp[0];
  float z = (score - rt * rt) / (temp * temp);
  float reset = 1.f / (1.f + expf(-z));  // saturates correctly at extremes
  float nc[6];
#pragma unroll
  for (int c = 0; c < 6; ++c) {
    float tc = 0.f, rc = 0.f;
#pragma unroll
    for (int e = 0; e < 6; ++e) {
      tc = fmaf(cp6[e], CT[e * 6 + c], tc);
      rc = fmaf(cp6[e], RT[e * 6 + c], rc);
    }
    nc[c] = reset * rc + (1.f - reset) * tc;
  }
  size_t obase = ((size_t)b * TT + t) * NV;
  for (int v = vi; v < NV; v += 4) {
    float o = 0.f;
#pragma unroll
    for (int c = 0; c < 6; ++c) o = fmaf(nc[c], OM[c * NV + v], o);
    out[obase + v] = o;
  }
}

extern "C" void kernel_launch(void* const* d_in, const int* in_sizes, int n_in,
                              void* d_out, int out_size, void* d_ws, size_t ws_size,
                              hipStream_t stream) {
  const int* x = (const int*)d_in[0];
  const float* ew = (const float*)d_in[1];
  const float* W = (const float*)d_in[2];
  const float* rtp = (const float*)d_in[3];
  const float* tp = (const float*)d_in[4];
  const float* CT = (const float*)d_in[5];
  const float* RT = (const float*)d_in[6];
  const float* OM = (const float*)d_in[7];
  float* out = (float*)d_out;
  float* cpt = (float*)d_ws;  // 24*8192 f32 = 786 KB

  hipLaunchKernelGGL(cp_kernel, dim3(256), dim3(128), 0, stream, x, ew, cpt);
  hipLaunchKernelGGL(sticky_fused, dim3(512), dim3(256), 0, stream,
                     W, cpt, rtp, tp, CT, RT, OM, out);
}